// Round 1
// baseline (191.620 us; speedup 1.0000x reference)
//
#include <hip/hip_runtime.h>
#include <hip/hip_bf16.h>

// Sparse gather-FFN:
//   B=32768 rows, L=8 layers, W=256 units/layer, K=16 gathers/unit.
//   vals starts as inputs (128 wide), each layer appends sigmoid(gather.wgt+b).
//   Output = last layer's 256 activations per row (float32).
//
// Strategy: LDS-gather-bound kernel. vals kept feature-major in LDS as
// float4 (4 batch rows interleaved) so each random gather is one
// ds_read_b128 (16 B/lane). Block = 256 threads (one per unit), 4 rows
// per block, grid = B/4 = 8192 blocks. 30.7 KB LDS -> 4 blocks/CU.

#define NB   32768
#define NIN  128
#define NL   8
#define NW   256
#define NK   16
#define RPB  4                      // batch rows per block
#define STORED (NIN + (NL - 1) * NW)  // 1920 features ever re-read

__global__ __launch_bounds__(256, 4)
void ffn_gather_kernel(const float* __restrict__ inputs,
                       const float* __restrict__ weights,
                       const float* __restrict__ biases,
                       const int*   __restrict__ edge_idx,
                       float* __restrict__ out)
{
    __shared__ float4 vals[STORED];   // vals[f] = feature f for rows r0..r0+3

    const int t = threadIdx.x;                       // 0..255, unit id
    const long long row0 = (long long)blockIdx.x * RPB;

    // ---- stage the 128 input features for 4 rows (feature-major) ----
    if (t < NIN) {
        float4 v;
        v.x = inputs[(row0 + 0) * NIN + t];
        v.y = inputs[(row0 + 1) * NIN + t];
        v.z = inputs[(row0 + 2) * NIN + t];
        v.w = inputs[(row0 + 3) * NIN + t];
        vals[t] = v;
    }
    __syncthreads();

    // ---- layers ----
    #pragma unroll
    for (int l = 0; l < NL; ++l) {
        const int base = (l * NW + t) * NK;
        const int4*   iq = (const int4*)(edge_idx + base);
        const float4* wq = (const float4*)(weights + base);

        const float b = biases[l * NW + t];
        float4 acc = make_float4(b, b, b, b);

        #pragma unroll
        for (int kk = 0; kk < NK / 4; ++kk) {
            const int4   i4 = iq[kk];
            const float4 w4 = wq[kk];
            const float4 v0 = vals[i4.x];
            const float4 v1 = vals[i4.y];
            const float4 v2 = vals[i4.z];
            const float4 v3 = vals[i4.w];
            acc.x = fmaf(w4.x, v0.x, acc.x);
            acc.y = fmaf(w4.x, v0.y, acc.y);
            acc.z = fmaf(w4.x, v0.z, acc.z);
            acc.w = fmaf(w4.x, v0.w, acc.w);
            acc.x = fmaf(w4.y, v1.x, acc.x);
            acc.y = fmaf(w4.y, v1.y, acc.y);
            acc.z = fmaf(w4.y, v1.z, acc.z);
            acc.w = fmaf(w4.y, v1.w, acc.w);
            acc.x = fmaf(w4.z, v2.x, acc.x);
            acc.y = fmaf(w4.z, v2.y, acc.y);
            acc.z = fmaf(w4.z, v2.z, acc.z);
            acc.w = fmaf(w4.z, v2.w, acc.w);
            acc.x = fmaf(w4.w, v3.x, acc.x);
            acc.y = fmaf(w4.w, v3.y, acc.y);
            acc.z = fmaf(w4.w, v3.z, acc.z);
            acc.w = fmaf(w4.w, v3.w, acc.w);
        }

        float4 s;
        s.x = 1.0f / (1.0f + __expf(-acc.x));
        s.y = 1.0f / (1.0f + __expf(-acc.y));
        s.z = 1.0f / (1.0f + __expf(-acc.z));
        s.w = 1.0f / (1.0f + __expf(-acc.w));

        if (l < NL - 1) {
            // layer-l writes land above every layer-l read region -> no
            // pre-write sync needed; one barrier before next layer's reads.
            vals[NIN + l * NW + t] = s;
        } else {
            out[(row0 + 0) * NW + t] = s.x;
            out[(row0 + 1) * NW + t] = s.y;
            out[(row0 + 2) * NW + t] = s.z;
            out[(row0 + 3) * NW + t] = s.w;
        }
        __syncthreads();
    }
}

extern "C" void kernel_launch(void* const* d_in, const int* in_sizes, int n_in,
                              void* d_out, int out_size, void* d_ws, size_t ws_size,
                              hipStream_t stream)
{
    const float* inputs   = (const float*)d_in[0];
    const float* weights  = (const float*)d_in[1];
    const float* biases   = (const float*)d_in[2];
    const int*   edge_idx = (const int*)d_in[3];
    float* out = (float*)d_out;

    dim3 grid(NB / RPB);   // 8192
    dim3 block(NW);        // 256
    ffn_gather_kernel<<<grid, block, 0, stream>>>(inputs, weights, biases,
                                                  edge_idx, out);
}

// Round 2
// 161.490 us; speedup vs baseline: 1.1866x; 1.1866x over previous
//
#include <hip/hip_runtime.h>
#include <hip/hip_bf16.h>

// Sparse gather-FFN, LDS-gather-bound.
// R2 change: vals stored as bf16, 8 batch rows packed per 16B LDS slot.
// Per-block gather traffic (L*W*K wave ds_read_b128) is independent of
// rows-per-block, so R=4->8 halves LDS instructions per row (the bound).
// Conflict factor (~1.7x, random f in 8 bank-groups) unchanged; total
// conflict cycles halve with instruction count.

#define NB   32768
#define NIN  128
#define NL   8
#define NW   256
#define NK   16
#define RPB  8                        // batch rows per block (8 bf16 = 16 B)
#define STORED (NIN + (NL - 1) * NW)  // 1920 features ever re-read

__device__ __forceinline__ unsigned bf16pair(float a, float b) {
    // RNE f32->bf16, packed (a in low 16, b in high 16)
    unsigned ua = __float_as_uint(a);
    unsigned ub = __float_as_uint(b);
    ua = (ua + 0x7fffu + ((ua >> 16) & 1u)) >> 16;
    ub = (ub + 0x7fffu + ((ub >> 16) & 1u)) >> 16;
    return ua | (ub << 16);
}

__device__ __forceinline__ void fma8(float acc[8], float w, uint4 p) {
    acc[0] = fmaf(w, __uint_as_float(p.x << 16), acc[0]);
    acc[1] = fmaf(w, __uint_as_float(p.x & 0xffff0000u), acc[1]);
    acc[2] = fmaf(w, __uint_as_float(p.y << 16), acc[2]);
    acc[3] = fmaf(w, __uint_as_float(p.y & 0xffff0000u), acc[3]);
    acc[4] = fmaf(w, __uint_as_float(p.z << 16), acc[4]);
    acc[5] = fmaf(w, __uint_as_float(p.z & 0xffff0000u), acc[5]);
    acc[6] = fmaf(w, __uint_as_float(p.w << 16), acc[6]);
    acc[7] = fmaf(w, __uint_as_float(p.w & 0xffff0000u), acc[7]);
}

__global__ __launch_bounds__(256, 4)
void ffn_gather_kernel(const float* __restrict__ inputs,
                       const float* __restrict__ weights,
                       const float* __restrict__ biases,
                       const int*   __restrict__ edge_idx,
                       float* __restrict__ out)
{
    __shared__ uint4 vals[STORED];   // vals[f] = 8 bf16 rows of feature f

    const int t = threadIdx.x;                       // 0..255, unit id
    const long long row0 = (long long)blockIdx.x * RPB;

    // ---- stage the 128 input features for 8 rows (feature-major, bf16) ----
    if (t < NIN) {
        float v[RPB];
        #pragma unroll
        for (int r = 0; r < RPB; ++r) v[r] = inputs[(row0 + r) * NIN + t];
        uint4 p;
        p.x = bf16pair(v[0], v[1]);
        p.y = bf16pair(v[2], v[3]);
        p.z = bf16pair(v[4], v[5]);
        p.w = bf16pair(v[6], v[7]);
        vals[t] = p;
    }
    __syncthreads();

    // ---- layers ----
    #pragma unroll
    for (int l = 0; l < NL; ++l) {
        const int base = (l * NW + t) * NK;
        const int4*   iq = (const int4*)(edge_idx + base);
        const float4* wq = (const float4*)(weights + base);

        const float b = biases[l * NW + t];
        float acc[RPB];
        #pragma unroll
        for (int r = 0; r < RPB; ++r) acc[r] = b;

        #pragma unroll
        for (int kk = 0; kk < NK / 4; ++kk) {
            const int4   i4 = iq[kk];
            const float4 w4 = wq[kk];
            const uint4 p0 = vals[i4.x];
            const uint4 p1 = vals[i4.y];
            const uint4 p2 = vals[i4.z];
            const uint4 p3 = vals[i4.w];
            fma8(acc, w4.x, p0);
            fma8(acc, w4.y, p1);
            fma8(acc, w4.z, p2);
            fma8(acc, w4.w, p3);
        }

        float s[RPB];
        #pragma unroll
        for (int r = 0; r < RPB; ++r)
            s[r] = 1.0f / (1.0f + __expf(-acc[r]));

        if (l < NL - 1) {
            // layer-l writes land above every layer-l read region -> no
            // pre-write sync needed; one barrier before next layer's reads.
            uint4 p;
            p.x = bf16pair(s[0], s[1]);
            p.y = bf16pair(s[2], s[3]);
            p.z = bf16pair(s[4], s[5]);
            p.w = bf16pair(s[6], s[7]);
            vals[NIN + l * NW + t] = p;
        } else {
            // final layer: fp32 straight to out, no bf16 roundtrip
            #pragma unroll
            for (int r = 0; r < RPB; ++r)
                out[(row0 + r) * NW + t] = s[r];
        }
        __syncthreads();
    }
}

extern "C" void kernel_launch(void* const* d_in, const int* in_sizes, int n_in,
                              void* d_out, int out_size, void* d_ws, size_t ws_size,
                              hipStream_t stream)
{
    const float* inputs   = (const float*)d_in[0];
    const float* weights  = (const float*)d_in[1];
    const float* biases   = (const float*)d_in[2];
    const int*   edge_idx = (const int*)d_in[3];
    float* out = (float*)d_out;

    dim3 grid(NB / RPB);   // 4096
    dim3 block(NW);        // 256
    ffn_gather_kernel<<<grid, block, 0, stream>>>(inputs, weights, biases,
                                                  edge_idx, out);
}